// Round 3
// baseline (209.902 us; speedup 1.0000x reference)
//
#include <hip/hip_runtime.h>
#include <cmath>

namespace {
constexpr int NB = 16384;
constexpr int NS = 50;
constexpr int NK = 5;
constexpr int NH = 32;

typedef __attribute__((ext_vector_type(8))) short bf16x8;
typedef __attribute__((ext_vector_type(4))) float f32x4;

__device__ __forceinline__ float wsum64(float v) {
#pragma unroll
  for (int off = 32; off; off >>= 1) v += __shfl_xor(v, off, 64);
  return v;
}

__device__ __forceinline__ float sigm(float x) { return 1.0f / (1.0f + expf(-x)); }

__device__ __forceinline__ unsigned short f2bf(float f) {
  union { float f; unsigned u; } v; v.f = f;
  unsigned r = v.u + 0x7fffu + ((v.u >> 16) & 1u);
  return (unsigned short)(r >> 16);
}

// ---- Kernel 1: embeddings, sim, top-5, x @ au_W1 via MFMA, au-BN stats ------
// 256 thr = 4 waves; 16 rows/block. x row = [hist_w(64), ic(64)] (K=128),
// cross handled as f32 rank-1 fixup.
__global__ __launch_bounds__(256) void k1(
    const int* __restrict__ iid, const int* __restrict__ aid,
    const int* __restrict__ hist_iid, const int* __restrict__ hist_aid,
    const int* __restrict__ hist_rate,
    const float* __restrict__ item_tab, const float* __restrict__ cate_tab,
    const float* __restrict__ au_W1, const float* __restrict__ au_b1,
    float* __restrict__ ws_y, float* __restrict__ ws_w,
    int* __restrict__ ws_hi, int* __restrict__ ws_ha, int* __restrict__ ws_hr,
    double* __restrict__ g_au_sum, double* __restrict__ g_au_sq)
{
  const int tid = threadIdx.x;
  const int lane = tid & 63;
  const int wv = tid >> 6;

  __shared__ alignas(16) unsigned short w1t[48][136]; // B: [n][k], bf16, k<128
  __shared__ alignas(16) unsigned short xb[80][136];  // A: [m][k], bf16, m=lm*5+kk
  __shared__ float icsh[4][64];
  __shared__ float crossm[80];
  __shared__ float w1c[36], b1s[36];
  __shared__ float psum[36], psq[36];

  // stage W1 (skip row 64 = cross row; K remapped to 128)
  for (int e = tid; e < 48 * 136; e += 256) {
    const int n = e / 136, k = e - 136 * n;
    float v = 0.f;
    if (n < 36 && k < 128) {
      const int i = (k < 64) ? k : (k + 1);
      v = au_W1[i * 36 + n];
    }
    w1t[n][k] = f2bf(v);
  }
  if (tid < 36) {
    w1c[tid] = au_W1[64 * 36 + tid];
    b1s[tid] = au_b1[tid];
    psum[tid] = 0.f; psq[tid] = 0.f;
  }

  for (int r = 0; r < 4; r++) {
    const int row = blockIdx.x * 16 + r * 4 + wv;
    const int lm = r * 4 + wv;

    const int iv = iid[row];
    const int cv = aid[row];
    const float ic = (lane < 32) ? item_tab[iv * NH + lane] : cate_tab[cv * NH + lane - 32];
    icsh[wv][lane] = ic;
    const float n1 = sqrtf(wsum64(ic * ic));

    int hi = 0, ha = 0, rv = 0;
    float dotv = 0.f, sim = -INFINITY;
    if (lane < NS) {
      hi = hist_iid[row * NS + lane];
      ha = hist_aid[row * NS + lane];
      rv = hist_rate[row * NS + lane];
      const float4* ip = reinterpret_cast<const float4*>(item_tab + (size_t)hi * NH);
      const float4* cp = reinterpret_cast<const float4*>(cate_tab + (size_t)ha * NH);
      const float* ics = icsh[wv];
      float n2sq = 0.f;
#pragma unroll
      for (int q = 0; q < 8; q++) {
        float4 a = ip[q];
        dotv += ics[4*q+0]*a.x + ics[4*q+1]*a.y + ics[4*q+2]*a.z + ics[4*q+3]*a.w;
        n2sq += a.x*a.x + a.y*a.y + a.z*a.z + a.w*a.w;
      }
#pragma unroll
      for (int q = 0; q < 8; q++) {
        float4 a = cp[q];
        dotv += ics[32+4*q+0]*a.x + ics[32+4*q+1]*a.y + ics[32+4*q+2]*a.z + ics[32+4*q+3]*a.w;
        n2sq += a.x*a.x + a.y*a.y + a.z*a.z + a.w*a.w;
      }
      sim = dotv / fmaxf(n1 * sqrtf(n2sq), 1e-8f);
    }

    // top-5: descending value, ascending-index tie-break
    float simw = sim;
    const int si = (lane < NS) ? lane : 1000;
    float vals[NK]; int idxs[NK];
#pragma unroll
    for (int rr = 0; rr < NK; rr++) {
      float v = simw; int ii = si;
#pragma unroll
      for (int off = 32; off; off >>= 1) {
        float ov = __shfl_xor(v, off, 64);
        int   oi = __shfl_xor(ii, off, 64);
        if (ov > v || (ov == v && oi < ii)) { v = ov; ii = oi; }
      }
      vals[rr] = v; idxs[rr] = ii;
      if (si == ii) simw = -INFINITY;
    }

    const float ssumw = vals[0] + vals[1] + vals[2] + vals[3] + vals[4] + 1e-8f;
#pragma unroll
    for (int k = 0; k < NK; k++) {
      const float wk = vals[k] / ssumw;
      const float crossk = wk * __shfl(dotv, idxs[k], 64);
      const int hik = __shfl(hi, idxs[k], 64);
      const int hak = __shfl(ha, idxs[k], 64);
      const int rvk = __shfl(rv, idxs[k], 64);
      const float e = (lane < 32) ? item_tab[hik * NH + lane] : cate_tab[hak * NH + lane - 32];
      const int m = lm * 5 + k;
      xb[m][lane] = f2bf(wk * e);
      xb[m][64 + lane] = f2bf(ic);
      if (lane == 0) crossm[m] = crossk;
      if (lane == k) {
        ws_w[row * NK + k] = wk;
        ws_hi[row * NK + k] = hik;
        ws_ha[row * NK + k] = hak;
        ws_hr[row * NK + k] = rvk;
      }
    }
  }
  __syncthreads();

  // MFMA GEMM: M=80 (5 tiles), N=36->48 (3 tiles), K=128 (4 steps)
  const int l15 = lane & 15, lhi = lane >> 4;
  for (int t = wv; t < 15; t += 4) {
    const int mt = t / 3, nt = t - 3 * mt;
    f32x4 acc = {0.f, 0.f, 0.f, 0.f};
#pragma unroll
    for (int ks = 0; ks < 4; ks++) {
      const int k0 = ks * 32 + lhi * 8;
      const bf16x8 a = *reinterpret_cast<const bf16x8*>(&xb[mt * 16 + l15][k0]);
      const bf16x8 b = *reinterpret_cast<const bf16x8*>(&w1t[nt * 16 + l15][k0]);
      acc = __builtin_amdgcn_mfma_f32_16x16x32_bf16(a, b, acc, 0, 0, 0);
    }
    const int n = nt * 16 + l15;
    if (n < 36) {
      const float w1cn = w1c[n], b1n = b1s[n];
      float ls = 0.f, lq = 0.f;
#pragma unroll
      for (int reg = 0; reg < 4; reg++) {
        const int m = mt * 16 + 4 * lhi + reg;
        const float y = acc[reg] + b1n + crossm[m] * w1cn;
        ws_y[(size_t)(blockIdx.x * 80 + m) * 36 + n] = y;
        ls += y; lq += y * y;
      }
      atomicAdd(&psum[n], ls);
      atomicAdd(&psq[n], lq);
    }
  }
  __syncthreads();
  if (tid < 36) {
    atomicAdd(&g_au_sum[tid], (double)psum[tid]);
    atomicAdd(&g_au_sq[tid], (double)psq[tid]);
  }
}

// ---- Kernel 3: dice3, au_out, final_hist, res @ l1_W via MFMA, d1 stats -----
// 256 thr = 4 waves; 16 rows/block. M=16, N=80 (5 tiles), K=160 (5 steps).
__global__ __launch_bounds__(256) void k3(
    const int* __restrict__ iid, const int* __restrict__ aid,
    const float* __restrict__ item_tab, const float* __restrict__ cate_tab,
    const float* __restrict__ rate_tab,
    const float* __restrict__ au_alpha, const float* __restrict__ au_beta,
    const float* __restrict__ au_gamma, const float* __restrict__ au_bbeta,
    const float* __restrict__ au_W2, const float* __restrict__ au_b2,
    const float* __restrict__ l1_W, const float* __restrict__ l1_b,
    const float* __restrict__ ws_y, const float* __restrict__ ws_w,
    const int* __restrict__ ws_hi, const int* __restrict__ ws_ha,
    const int* __restrict__ ws_hr,
    const double* __restrict__ g_au_sum, const double* __restrict__ g_au_sq,
    float* __restrict__ ws_h1, double* __restrict__ g_d1_sum, double* __restrict__ g_d1_sq)
{
  const int tid = threadIdx.x, lane = tid & 63, wv = tid >> 6;
  __shared__ alignas(16) unsigned short l1t[80][168]; // B: [n][k], k<160
  __shared__ alignas(16) unsigned short resb[16][168];
  __shared__ float asc[36], bsc[36];
  __shared__ float psum[80], psq[80];

  for (int e = tid; e < 80 * 168; e += 256) {
    const int n = e / 168, k = e - 168 * n;
    l1t[n][k] = (k < 160) ? f2bf(l1_W[k * 80 + n]) : (unsigned short)0;
  }
  if (tid < 36) {
    const double m = g_au_sum[tid] * (1.0 / ((double)NB * NK));
    const double var = g_au_sq[tid] * (1.0 / ((double)NB * NK)) - m * m;
    const float rstd = (float)(1.0 / sqrt(var + 1e-8));
    const float g = au_gamma[tid] * rstd;
    asc[tid] = g; bsc[tid] = au_bbeta[tid] - (float)m * g;
  }
  if (tid < 80) { psum[tid] = 0.f; psq[tid] = 0.f; }
  __syncthreads();

  float aj = 0, bj = 0, betaj = 0, alphaj = 0, w2j = 0;
  if (lane < 36) {
    aj = asc[lane]; bj = bsc[lane];
    betaj = au_beta[lane]; alphaj = au_alpha[lane]; w2j = au_W2[lane];
  }
  const float bias2 = au_b2[0];

  for (int r = 0; r < 4; r++) {
    const int row = blockIdx.x * 16 + r * 4 + wv;
    const int lm = r * 4 + wv;

    float aout[NK];
#pragma unroll
    for (int k = 0; k < NK; k++) {
      float p = 0.f;
      if (lane < 36) {
        const float yv = ws_y[(size_t)row * 180 + k * 36 + lane];
        const float bn = yv * aj + bj;
        const float xn = sigm(betaj * bn);
        p = (alphaj * (1.f - xn) * yv + xn * yv) * w2j;
      }
      aout[k] = wsum64(p) + bias2;
    }

    const int iv = iid[row], cv = aid[row];
    const float ic = (lane < 32) ? item_tab[iv * NH + lane] : cate_tab[cv * NH + lane - 32];
    float fh0 = 0.f, fh1 = 0.f;
#pragma unroll
    for (int k = 0; k < NK; k++) {
      const int hik = ws_hi[row * NK + k];
      const int hak = ws_ha[row * NK + k];
      const int rvk = ws_hr[row * NK + k];
      const float wk = ws_w[row * NK + k];
      const float e = (lane < 32) ? item_tab[hik * NH + lane] : cate_tab[hak * NH + lane - 32];
      fh0 = fmaf(wk * e, aout[k], fh0);
      if (lane < 32) fh1 = fmaf(rate_tab[rvk * NH + lane], aout[k], fh1);
    }
    resb[lm][lane] = f2bf(ic);
    resb[lm][64 + lane] = f2bf(fh0);
    if (lane < 32) resb[lm][128 + lane] = f2bf(fh1);
  }
  __syncthreads();

  const int l15 = lane & 15, lhi = lane >> 4;
  for (int nt = wv; nt < 5; nt += 4) {
    f32x4 acc = {0.f, 0.f, 0.f, 0.f};
#pragma unroll
    for (int ks = 0; ks < 5; ks++) {
      const int k0 = ks * 32 + lhi * 8;
      const bf16x8 a = *reinterpret_cast<const bf16x8*>(&resb[l15][k0]);
      const bf16x8 b = *reinterpret_cast<const bf16x8*>(&l1t[nt * 16 + l15][k0]);
      acc = __builtin_amdgcn_mfma_f32_16x16x32_bf16(a, b, acc, 0, 0, 0);
    }
    const int n = nt * 16 + l15;
    const float bn = l1_b[n];
    float ls = 0.f, lq = 0.f;
#pragma unroll
    for (int reg = 0; reg < 4; reg++) {
      const int m = 4 * lhi + reg;
      const float h = acc[reg] + bn;
      ws_h1[(size_t)(blockIdx.x * 16 + m) * 80 + n] = h;
      ls += h; lq += h * h;
    }
    atomicAdd(&psum[n], ls);
    atomicAdd(&psq[n], lq);
  }
  __syncthreads();
  if (tid < 80) {
    atomicAdd(&g_d1_sum[tid], (double)psum[tid]);
    atomicAdd(&g_d1_sq[tid], (double)psq[tid]);
  }
}

// ---- Kernel 5: dice2(h1), h @ l2_W via MFMA, d2 stats -----------------------
// M=16, N=40->48 (3 tiles), K=80->96 (3 steps, zero-padded).
__global__ __launch_bounds__(256) void k5(
    const float* __restrict__ d1_alpha, const float* __restrict__ d1_beta,
    const float* __restrict__ d1_gamma, const float* __restrict__ d1_bbeta,
    const float* __restrict__ l2_W, const float* __restrict__ l2_b,
    const float* __restrict__ ws_h1,
    const double* __restrict__ g_d1_sum, const double* __restrict__ g_d1_sq,
    float* __restrict__ ws_h2, double* __restrict__ g_d2_sum, double* __restrict__ g_d2_sq)
{
  const int tid = threadIdx.x, lane = tid & 63, wv = tid >> 6;
  __shared__ alignas(16) unsigned short l2t[48][104];
  __shared__ alignas(16) unsigned short h1b[16][104];
  __shared__ float a1[80], c1[80];
  __shared__ float psum[40], psq[40];

  for (int e = tid; e < 48 * 104; e += 256) {
    const int n = e / 104, k = e - 104 * n;
    l2t[n][k] = (n < 40 && k < 80) ? f2bf(l2_W[k * 40 + n]) : (unsigned short)0;
  }
  if (tid < 80) {
    const double m = g_d1_sum[tid] * (1.0 / (double)NB);
    const double var = g_d1_sq[tid] * (1.0 / (double)NB) - m * m;
    const float rstd = (float)(1.0 / sqrt(var + 1e-8));
    const float g = d1_gamma[tid] * rstd;
    a1[tid] = g; c1[tid] = d1_bbeta[tid] - (float)m * g;
  }
  if (tid < 40) { psum[tid] = 0.f; psq[tid] = 0.f; }
  __syncthreads();

  for (int r = 0; r < 4; r++) {
    const int row = blockIdx.x * 16 + r * 4 + wv;
    const int lm = r * 4 + wv;
    {
      const float v = ws_h1[(size_t)row * 80 + lane];
      const float bn = v * a1[lane] + c1[lane];
      const float xn = sigm(d1_beta[lane] * bn);
      h1b[lm][lane] = f2bf(d1_alpha[lane] * (1.f - xn) * v + xn * v);
    }
    const int o = 64 + lane;
    if (lane < 16) {
      const float v = ws_h1[(size_t)row * 80 + o];
      const float bn = v * a1[o] + c1[o];
      const float xn = sigm(d1_beta[o] * bn);
      h1b[lm][o] = f2bf(d1_alpha[o] * (1.f - xn) * v + xn * v);
    } else if (lane < 32) {
      h1b[lm][o] = 0;  // zero pad k=80..95
    }
  }
  __syncthreads();

  const int l15 = lane & 15, lhi = lane >> 4;
  if (wv < 3) {
    const int nt = wv;
    f32x4 acc = {0.f, 0.f, 0.f, 0.f};
#pragma unroll
    for (int ks = 0; ks < 3; ks++) {
      const int k0 = ks * 32 + lhi * 8;
      const bf16x8 a = *reinterpret_cast<const bf16x8*>(&h1b[l15][k0]);
      const bf16x8 b = *reinterpret_cast<const bf16x8*>(&l2t[nt * 16 + l15][k0]);
      acc = __builtin_amdgcn_mfma_f32_16x16x32_bf16(a, b, acc, 0, 0, 0);
    }
    const int n = nt * 16 + l15;
    if (n < 40) {
      const float bn = l2_b[n];
      float ls = 0.f, lq = 0.f;
#pragma unroll
      for (int reg = 0; reg < 4; reg++) {
        const int m = 4 * lhi + reg;
        const float h = acc[reg] + bn;
        ws_h2[(size_t)(blockIdx.x * 16 + m) * 40 + n] = h;
        ls += h; lq += h * h;
      }
      atomicAdd(&psum[n], ls);
      atomicAdd(&psq[n], lq);
    }
  }
  __syncthreads();
  if (tid < 40) {
    atomicAdd(&g_d2_sum[tid], (double)psum[tid]);
    atomicAdd(&g_d2_sq[tid], (double)psq[tid]);
  }
}

// ---- Kernel 7: dice2(h2), logits, probs, loss -------------------------------
__global__ __launch_bounds__(256) void k7(
    const int* __restrict__ lb,
    const float* __restrict__ d2_alpha, const float* __restrict__ d2_beta,
    const float* __restrict__ d2_gamma, const float* __restrict__ d2_bbeta,
    const float* __restrict__ l3_W, const float* __restrict__ l3_b,
    const float* __restrict__ ws_h2,
    const double* __restrict__ g_d2_sum, const double* __restrict__ g_d2_sq,
    float* __restrict__ out, double* __restrict__ g_loss)
{
  const int tid = threadIdx.x, lane = tid & 63, wv = tid >> 6;
  __shared__ float a2[40], c2[40];
  __shared__ float wls[4];
  if (tid < 40) {
    const double m = g_d2_sum[tid] * (1.0 / (double)NB);
    const double var = g_d2_sq[tid] * (1.0 / (double)NB) - m * m;
    const float rstd = (float)(1.0 / sqrt(var + 1e-8));
    const float g = d2_gamma[tid] * rstd;
    a2[tid] = g; c2[tid] = d2_bbeta[tid] - (float)m * g;
  }
  __syncthreads();

  float wj = 0, b2j = 0, c2j = 0, betaj = 0, alphaj = 0;
  if (lane < 40) {
    wj = l3_W[lane]; b2j = a2[lane]; c2j = c2[lane];
    betaj = d2_beta[lane]; alphaj = d2_alpha[lane];
  }
  const float b3 = l3_b[0];

  float lacc = 0.f;
  for (int r = 0; r < 4; r++) {
    const int row = blockIdx.x * 16 + r * 4 + wv;
    float p = 0.f;
    if (lane < 40) {
      const float v = ws_h2[(size_t)row * 40 + lane];
      const float bn = v * b2j + c2j;
      const float xn = sigm(betaj * bn);
      p = (alphaj * (1.f - xn) * v + xn * v) * wj;
    }
    const float logit = wsum64(p) + b3;
    if (lane == 0) {
      out[row] = 1.f / (1.f + expf(-logit));
      const float lab = (float)lb[row];
      lacc += fmaxf(logit, 0.f) - logit * lab + log1pf(expf(-fabsf(logit)));
    }
  }
  if (lane == 0) wls[wv] = lacc;
  __syncthreads();
  if (tid == 0) atomicAdd(g_loss, (double)(wls[0] + wls[1] + wls[2] + wls[3]));
}

__global__ void k8(const double* __restrict__ g_loss, float* __restrict__ out) {
  out[NB] = (float)(g_loss[0] * (1.0 / (double)NB));
}

} // namespace

extern "C" void kernel_launch(void* const* d_in, const int* in_sizes, int n_in,
                              void* d_out, int out_size, void* d_ws, size_t ws_size,
                              hipStream_t stream) {
  const int* iid       = (const int*)d_in[0];
  const int* aid       = (const int*)d_in[1];
  const int* lb        = (const int*)d_in[2];
  const int* hist_iid  = (const int*)d_in[3];
  const int* hist_aid  = (const int*)d_in[4];
  const int* hist_rate = (const int*)d_in[5];
  const float* item_tab = (const float*)d_in[6];
  const float* cate_tab = (const float*)d_in[7];
  const float* rate_tab = (const float*)d_in[8];
  const float* au_W1    = (const float*)d_in[9];
  const float* au_b1    = (const float*)d_in[10];
  const float* au_alpha = (const float*)d_in[11];
  const float* au_beta  = (const float*)d_in[12];
  const float* au_gamma = (const float*)d_in[13];
  const float* au_bbeta = (const float*)d_in[14];
  const float* au_W2    = (const float*)d_in[15];
  const float* au_b2    = (const float*)d_in[16];
  const float* l1_W     = (const float*)d_in[17];
  const float* l1_b     = (const float*)d_in[18];
  const float* d1_alpha = (const float*)d_in[19];
  const float* d1_beta  = (const float*)d_in[20];
  const float* d1_gamma = (const float*)d_in[21];
  const float* d1_bbeta = (const float*)d_in[22];
  const float* l2_W     = (const float*)d_in[23];
  const float* l2_b     = (const float*)d_in[24];
  const float* d2_alpha = (const float*)d_in[25];
  const float* d2_beta  = (const float*)d_in[26];
  const float* d2_gamma = (const float*)d_in[27];
  const float* d2_bbeta = (const float*)d_in[28];
  const float* l3_W     = (const float*)d_in[29];
  const float* l3_b     = (const float*)d_in[30];
  float* out = (float*)d_out;

  double* g = (double*)d_ws;
  double* g_au_sum = g;
  double* g_au_sq  = g + 36;
  double* g_d1_sum = g + 72;
  double* g_d1_sq  = g + 152;
  double* g_d2_sum = g + 232;
  double* g_d2_sq  = g + 272;
  double* g_loss   = g + 312;
  float* fbase  = (float*)((char*)d_ws + 4096);
  float* ws_y   = fbase;                       // NB*180
  float* ws_w   = fbase + (size_t)NB * 180;    // NB*5
  float* ws_h1  = fbase + (size_t)NB * 185;    // NB*80
  float* ws_h2  = fbase + (size_t)NB * 265;    // NB*40
  int*   ws_hi  = (int*)(fbase + (size_t)NB * 305);  // NB*5
  int*   ws_ha  = ws_hi + (size_t)NB * NK;
  int*   ws_hr  = ws_ha + (size_t)NB * NK;

  hipMemsetAsync(d_ws, 0, 313 * sizeof(double), stream);
  dim3 grd(NB / 16);
  k1<<<grd, 256, 0, stream>>>(iid, aid, hist_iid, hist_aid, hist_rate,
                              item_tab, cate_tab, au_W1, au_b1,
                              ws_y, ws_w, ws_hi, ws_ha, ws_hr, g_au_sum, g_au_sq);
  k3<<<grd, 256, 0, stream>>>(iid, aid, item_tab, cate_tab, rate_tab,
                              au_alpha, au_beta, au_gamma, au_bbeta, au_W2, au_b2,
                              l1_W, l1_b, ws_y, ws_w, ws_hi, ws_ha, ws_hr,
                              g_au_sum, g_au_sq, ws_h1, g_d1_sum, g_d1_sq);
  k5<<<grd, 256, 0, stream>>>(d1_alpha, d1_beta, d1_gamma, d1_bbeta, l2_W, l2_b,
                              ws_h1, g_d1_sum, g_d1_sq, ws_h2, g_d2_sum, g_d2_sq);
  k7<<<grd, 256, 0, stream>>>(lb, d2_alpha, d2_beta, d2_gamma, d2_bbeta, l3_W, l3_b,
                              ws_h2, g_d2_sum, g_d2_sq, out, g_loss);
  k8<<<1, 1, 0, stream>>>(g_loss, out);
}

// Round 4
// 195.930 us; speedup vs baseline: 1.0713x; 1.0713x over previous
//
#include <hip/hip_runtime.h>
#include <cmath>

namespace {
constexpr int NB = 16384;
constexpr int NS = 50;
constexpr int NK = 5;
constexpr int NH = 32;

typedef __attribute__((ext_vector_type(8))) short bf16x8;
typedef __attribute__((ext_vector_type(4))) float f32x4;

__device__ __forceinline__ float wsum64(float v) {
#pragma unroll
  for (int off = 32; off; off >>= 1) v += __shfl_xor(v, off, 64);
  return v;
}

__device__ __forceinline__ float sigm(float x) { return 1.0f / (1.0f + expf(-x)); }

__device__ __forceinline__ unsigned short f2bf(float f) {
  union { float f; unsigned u; } v; v.f = f;
  unsigned r = v.u + 0x7fffu + ((v.u >> 16) & 1u);
  return (unsigned short)(r >> 16);
}

// ---- Kernel 1: embeddings, sim, top-5, x @ au_W1 via MFMA, au-BN stats ------
// 512 thr = 8 waves; 16 rows/block, 2 rows per wave.
__global__ __launch_bounds__(512) void k1(
    const int* __restrict__ iid, const int* __restrict__ aid,
    const int* __restrict__ hist_iid, const int* __restrict__ hist_aid,
    const int* __restrict__ hist_rate,
    const float* __restrict__ item_tab, const float* __restrict__ cate_tab,
    const float* __restrict__ au_W1, const float* __restrict__ au_b1,
    float* __restrict__ ws_y, float* __restrict__ ws_w,
    int* __restrict__ ws_hi, int* __restrict__ ws_ha, int* __restrict__ ws_hr,
    double* __restrict__ g_au_sum, double* __restrict__ g_au_sq)
{
  const int tid = threadIdx.x;
  const int lane = tid & 63;
  const int wv = tid >> 6;

  __shared__ alignas(16) unsigned short w1t[48][136]; // B: [n][k], bf16, k<128
  __shared__ alignas(16) unsigned short xb[80][136];  // A: [m][k], bf16, m=lm*5+kk
  __shared__ float icsh[8][64];
  __shared__ float crossm[80];
  __shared__ float w1c[36], b1s[36];
  __shared__ float psum[36], psq[36];

  // stage W1 (skip row 64 = cross row; K remapped to 128)
  for (int e = tid; e < 48 * 136; e += 512) {
    const int n = e / 136, k = e - 136 * n;
    float v = 0.f;
    if (n < 36 && k < 128) {
      const int i = (k < 64) ? k : (k + 1);
      v = au_W1[i * 36 + n];
    }
    w1t[n][k] = f2bf(v);
  }
  if (tid < 36) {
    w1c[tid] = au_W1[64 * 36 + tid];
    b1s[tid] = au_b1[tid];
    psum[tid] = 0.f; psq[tid] = 0.f;
  }

  for (int r = 0; r < 2; r++) {
    const int lm = r * 8 + wv;
    const int row = blockIdx.x * 16 + lm;

    const int iv = iid[row];
    const int cv = aid[row];
    const float ic = (lane < 32) ? item_tab[iv * NH + lane] : cate_tab[cv * NH + lane - 32];
    icsh[wv][lane] = ic;
    const float n1 = sqrtf(wsum64(ic * ic));

    int hi = 0, ha = 0, rv = 0;
    float dotv = 0.f, sim = -INFINITY;
    if (lane < NS) {
      hi = hist_iid[row * NS + lane];
      ha = hist_aid[row * NS + lane];
      rv = hist_rate[row * NS + lane];
      const float4* ip = reinterpret_cast<const float4*>(item_tab + (size_t)hi * NH);
      const float4* cp = reinterpret_cast<const float4*>(cate_tab + (size_t)ha * NH);
      const float* ics = icsh[wv];
      float n2sq = 0.f;
#pragma unroll
      for (int q = 0; q < 8; q++) {
        float4 a = ip[q];
        dotv += ics[4*q+0]*a.x + ics[4*q+1]*a.y + ics[4*q+2]*a.z + ics[4*q+3]*a.w;
        n2sq += a.x*a.x + a.y*a.y + a.z*a.z + a.w*a.w;
      }
#pragma unroll
      for (int q = 0; q < 8; q++) {
        float4 a = cp[q];
        dotv += ics[32+4*q+0]*a.x + ics[32+4*q+1]*a.y + ics[32+4*q+2]*a.z + ics[32+4*q+3]*a.w;
        n2sq += a.x*a.x + a.y*a.y + a.z*a.z + a.w*a.w;
      }
      sim = dotv / fmaxf(n1 * sqrtf(n2sq), 1e-8f);
    }

    // top-5: descending value, ascending-index tie-break
    float simw = sim;
    const int si = (lane < NS) ? lane : 1000;
    float vals[NK]; int idxs[NK];
#pragma unroll
    for (int rr = 0; rr < NK; rr++) {
      float v = simw; int ii = si;
#pragma unroll
      for (int off = 32; off; off >>= 1) {
        float ov = __shfl_xor(v, off, 64);
        int   oi = __shfl_xor(ii, off, 64);
        if (ov > v || (ov == v && oi < ii)) { v = ov; ii = oi; }
      }
      vals[rr] = v; idxs[rr] = ii;
      if (si == ii) simw = -INFINITY;
    }

    const float ssumw = vals[0] + vals[1] + vals[2] + vals[3] + vals[4] + 1e-8f;
#pragma unroll
    for (int k = 0; k < NK; k++) {
      const float wk = vals[k] / ssumw;
      const float crossk = wk * __shfl(dotv, idxs[k], 64);
      const int hik = __shfl(hi, idxs[k], 64);
      const int hak = __shfl(ha, idxs[k], 64);
      const int rvk = __shfl(rv, idxs[k], 64);
      const float e = (lane < 32) ? item_tab[hik * NH + lane] : cate_tab[hak * NH + lane - 32];
      const int m = lm * 5 + k;
      xb[m][lane] = f2bf(wk * e);
      xb[m][64 + lane] = f2bf(ic);
      if (lane == 0) crossm[m] = crossk;
      if (lane == k) {
        ws_w[row * NK + k] = wk;
        ws_hi[row * NK + k] = hik;
        ws_ha[row * NK + k] = hak;
        ws_hr[row * NK + k] = rvk;
      }
    }
  }
  __syncthreads();

  // MFMA GEMM: M=80 (5 tiles), N=36->48 (3 tiles), K=128 (4 steps)
  const int l15 = lane & 15, lhi = lane >> 4;
  for (int t = wv; t < 15; t += 8) {
    const int mt = t / 3, nt = t - 3 * mt;
    f32x4 acc = {0.f, 0.f, 0.f, 0.f};
#pragma unroll
    for (int ks = 0; ks < 4; ks++) {
      const int k0 = ks * 32 + lhi * 8;
      const bf16x8 a = *reinterpret_cast<const bf16x8*>(&xb[mt * 16 + l15][k0]);
      const bf16x8 b = *reinterpret_cast<const bf16x8*>(&w1t[nt * 16 + l15][k0]);
      acc = __builtin_amdgcn_mfma_f32_16x16x32_bf16(a, b, acc, 0, 0, 0);
    }
    const int n = nt * 16 + l15;
    if (n < 36) {
      const float w1cn = w1c[n], b1n = b1s[n];
      float ls = 0.f, lq = 0.f;
#pragma unroll
      for (int reg = 0; reg < 4; reg++) {
        const int m = mt * 16 + 4 * lhi + reg;
        const float y = acc[reg] + b1n + crossm[m] * w1cn;
        ws_y[(size_t)(blockIdx.x * 80 + m) * 36 + n] = y;
        ls += y; lq += y * y;
      }
      atomicAdd(&psum[n], ls);
      atomicAdd(&psq[n], lq);
    }
  }
  __syncthreads();
  if (tid < 36) {
    atomicAdd(&g_au_sum[tid], (double)psum[tid]);
    atomicAdd(&g_au_sq[tid], (double)psq[tid]);
  }
}

// ---- Kernel 3: dice3, au_out, final_hist, res @ l1_W via MFMA, d1 stats -----
// 512 thr = 8 waves; 16 rows/block, 2 rows per wave. M=16, N=80, K=160.
__global__ __launch_bounds__(512) void k3(
    const int* __restrict__ iid, const int* __restrict__ aid,
    const float* __restrict__ item_tab, const float* __restrict__ cate_tab,
    const float* __restrict__ rate_tab,
    const float* __restrict__ au_alpha, const float* __restrict__ au_beta,
    const float* __restrict__ au_gamma, const float* __restrict__ au_bbeta,
    const float* __restrict__ au_W2, const float* __restrict__ au_b2,
    const float* __restrict__ l1_W, const float* __restrict__ l1_b,
    const float* __restrict__ ws_y, const float* __restrict__ ws_w,
    const int* __restrict__ ws_hi, const int* __restrict__ ws_ha,
    const int* __restrict__ ws_hr,
    const double* __restrict__ g_au_sum, const double* __restrict__ g_au_sq,
    float* __restrict__ ws_h1, double* __restrict__ g_d1_sum, double* __restrict__ g_d1_sq)
{
  const int tid = threadIdx.x, lane = tid & 63, wv = tid >> 6;
  __shared__ alignas(16) unsigned short l1t[80][168]; // B: [n][k], k<160
  __shared__ alignas(16) unsigned short resb[16][168];
  __shared__ float asc[36], bsc[36];
  __shared__ float psum[80], psq[80];

  for (int e = tid; e < 80 * 168; e += 512) {
    const int n = e / 168, k = e - 168 * n;
    l1t[n][k] = (k < 160) ? f2bf(l1_W[k * 80 + n]) : (unsigned short)0;
  }
  if (tid < 36) {
    const double m = g_au_sum[tid] * (1.0 / ((double)NB * NK));
    const double var = g_au_sq[tid] * (1.0 / ((double)NB * NK)) - m * m;
    const float rstd = (float)(1.0 / sqrt(var + 1e-8));
    const float g = au_gamma[tid] * rstd;
    asc[tid] = g; bsc[tid] = au_bbeta[tid] - (float)m * g;
  }
  if (tid < 80) { psum[tid] = 0.f; psq[tid] = 0.f; }
  __syncthreads();

  float aj = 0, bj = 0, betaj = 0, alphaj = 0, w2j = 0;
  if (lane < 36) {
    aj = asc[lane]; bj = bsc[lane];
    betaj = au_beta[lane]; alphaj = au_alpha[lane]; w2j = au_W2[lane];
  }
  const float bias2 = au_b2[0];

  for (int r = 0; r < 2; r++) {
    const int lm = r * 8 + wv;
    const int row = blockIdx.x * 16 + lm;

    float aout[NK];
#pragma unroll
    for (int k = 0; k < NK; k++) {
      float p = 0.f;
      if (lane < 36) {
        const float yv = ws_y[(size_t)row * 180 + k * 36 + lane];
        const float bn = yv * aj + bj;
        const float xn = sigm(betaj * bn);
        p = (alphaj * (1.f - xn) * yv + xn * yv) * w2j;
      }
      aout[k] = wsum64(p) + bias2;
    }

    const int iv = iid[row], cv = aid[row];
    const float ic = (lane < 32) ? item_tab[iv * NH + lane] : cate_tab[cv * NH + lane - 32];
    float fh0 = 0.f, fh1 = 0.f;
#pragma unroll
    for (int k = 0; k < NK; k++) {
      const int hik = ws_hi[row * NK + k];
      const int hak = ws_ha[row * NK + k];
      const int rvk = ws_hr[row * NK + k];
      const float wk = ws_w[row * NK + k];
      const float e = (lane < 32) ? item_tab[hik * NH + lane] : cate_tab[hak * NH + lane - 32];
      fh0 = fmaf(wk * e, aout[k], fh0);
      if (lane < 32) fh1 = fmaf(rate_tab[rvk * NH + lane], aout[k], fh1);
    }
    resb[lm][lane] = f2bf(ic);
    resb[lm][64 + lane] = f2bf(fh0);
    if (lane < 32) resb[lm][128 + lane] = f2bf(fh1);
  }
  __syncthreads();

  const int l15 = lane & 15, lhi = lane >> 4;
  if (wv < 5) {
    const int nt = wv;
    f32x4 acc = {0.f, 0.f, 0.f, 0.f};
#pragma unroll
    for (int ks = 0; ks < 5; ks++) {
      const int k0 = ks * 32 + lhi * 8;
      const bf16x8 a = *reinterpret_cast<const bf16x8*>(&resb[l15][k0]);
      const bf16x8 b = *reinterpret_cast<const bf16x8*>(&l1t[nt * 16 + l15][k0]);
      acc = __builtin_amdgcn_mfma_f32_16x16x32_bf16(a, b, acc, 0, 0, 0);
    }
    const int n = nt * 16 + l15;
    const float bn = l1_b[n];
    float ls = 0.f, lq = 0.f;
#pragma unroll
    for (int reg = 0; reg < 4; reg++) {
      const int m = 4 * lhi + reg;
      const float h = acc[reg] + bn;
      ws_h1[(size_t)(blockIdx.x * 16 + m) * 80 + n] = h;
      ls += h; lq += h * h;
    }
    atomicAdd(&psum[n], ls);
    atomicAdd(&psq[n], lq);
  }
  __syncthreads();
  if (tid < 80) {
    atomicAdd(&g_d1_sum[tid], (double)psum[tid]);
    atomicAdd(&g_d1_sq[tid], (double)psq[tid]);
  }
}

// ---- Kernel 5: dice2(h1), h @ l2_W via MFMA, d2 stats -----------------------
// M=16, N=40->48 (3 tiles), K=80->96 (3 steps, zero-padded).
__global__ __launch_bounds__(256) void k5(
    const float* __restrict__ d1_alpha, const float* __restrict__ d1_beta,
    const float* __restrict__ d1_gamma, const float* __restrict__ d1_bbeta,
    const float* __restrict__ l2_W, const float* __restrict__ l2_b,
    const float* __restrict__ ws_h1,
    const double* __restrict__ g_d1_sum, const double* __restrict__ g_d1_sq,
    float* __restrict__ ws_h2, double* __restrict__ g_d2_sum, double* __restrict__ g_d2_sq)
{
  const int tid = threadIdx.x, lane = tid & 63, wv = tid >> 6;
  __shared__ alignas(16) unsigned short l2t[48][104];
  __shared__ alignas(16) unsigned short h1b[16][104];
  __shared__ float a1[80], c1[80];
  __shared__ float psum[40], psq[40];

  for (int e = tid; e < 48 * 104; e += 256) {
    const int n = e / 104, k = e - 104 * n;
    l2t[n][k] = (n < 40 && k < 80) ? f2bf(l2_W[k * 40 + n]) : (unsigned short)0;
  }
  if (tid < 80) {
    const double m = g_d1_sum[tid] * (1.0 / (double)NB);
    const double var = g_d1_sq[tid] * (1.0 / (double)NB) - m * m;
    const float rstd = (float)(1.0 / sqrt(var + 1e-8));
    const float g = d1_gamma[tid] * rstd;
    a1[tid] = g; c1[tid] = d1_bbeta[tid] - (float)m * g;
  }
  if (tid < 40) { psum[tid] = 0.f; psq[tid] = 0.f; }
  __syncthreads();

  for (int r = 0; r < 4; r++) {
    const int row = blockIdx.x * 16 + r * 4 + wv;
    const int lm = r * 4 + wv;
    {
      const float v = ws_h1[(size_t)row * 80 + lane];
      const float bn = v * a1[lane] + c1[lane];
      const float xn = sigm(d1_beta[lane] * bn);
      h1b[lm][lane] = f2bf(d1_alpha[lane] * (1.f - xn) * v + xn * v);
    }
    const int o = 64 + lane;
    if (lane < 16) {
      const float v = ws_h1[(size_t)row * 80 + o];
      const float bn = v * a1[o] + c1[o];
      const float xn = sigm(d1_beta[o] * bn);
      h1b[lm][o] = f2bf(d1_alpha[o] * (1.f - xn) * v + xn * v);
    } else if (lane < 32) {
      h1b[lm][o] = 0;  // zero pad k=80..95
    }
  }
  __syncthreads();

  const int l15 = lane & 15, lhi = lane >> 4;
  if (wv < 3) {
    const int nt = wv;
    f32x4 acc = {0.f, 0.f, 0.f, 0.f};
#pragma unroll
    for (int ks = 0; ks < 3; ks++) {
      const int k0 = ks * 32 + lhi * 8;
      const bf16x8 a = *reinterpret_cast<const bf16x8*>(&h1b[l15][k0]);
      const bf16x8 b = *reinterpret_cast<const bf16x8*>(&l2t[nt * 16 + l15][k0]);
      acc = __builtin_amdgcn_mfma_f32_16x16x32_bf16(a, b, acc, 0, 0, 0);
    }
    const int n = nt * 16 + l15;
    if (n < 40) {
      const float bn = l2_b[n];
      float ls = 0.f, lq = 0.f;
#pragma unroll
      for (int reg = 0; reg < 4; reg++) {
        const int m = 4 * lhi + reg;
        const float h = acc[reg] + bn;
        ws_h2[(size_t)(blockIdx.x * 16 + m) * 40 + n] = h;
        ls += h; lq += h * h;
      }
      atomicAdd(&psum[n], ls);
      atomicAdd(&psq[n], lq);
    }
  }
  __syncthreads();
  if (tid < 40) {
    atomicAdd(&g_d2_sum[tid], (double)psum[tid]);
    atomicAdd(&g_d2_sq[tid], (double)psq[tid]);
  }
}

// ---- Kernel 7: dice2(h2), logits, probs, loss -------------------------------
__global__ __launch_bounds__(256) void k7(
    const int* __restrict__ lb,
    const float* __restrict__ d2_alpha, const float* __restrict__ d2_beta,
    const float* __restrict__ d2_gamma, const float* __restrict__ d2_bbeta,
    const float* __restrict__ l3_W, const float* __restrict__ l3_b,
    const float* __restrict__ ws_h2,
    const double* __restrict__ g_d2_sum, const double* __restrict__ g_d2_sq,
    float* __restrict__ out, double* __restrict__ g_loss)
{
  const int tid = threadIdx.x, lane = tid & 63, wv = tid >> 6;
  __shared__ float a2[40], c2[40];
  __shared__ float wls[4];
  if (tid < 40) {
    const double m = g_d2_sum[tid] * (1.0 / (double)NB);
    const double var = g_d2_sq[tid] * (1.0 / (double)NB) - m * m;
    const float rstd = (float)(1.0 / sqrt(var + 1e-8));
    const float g = d2_gamma[tid] * rstd;
    a2[tid] = g; c2[tid] = d2_bbeta[tid] - (float)m * g;
  }
  __syncthreads();

  float wj = 0, b2j = 0, c2j = 0, betaj = 0, alphaj = 0;
  if (lane < 40) {
    wj = l3_W[lane]; b2j = a2[lane]; c2j = c2[lane];
    betaj = d2_beta[lane]; alphaj = d2_alpha[lane];
  }
  const float b3 = l3_b[0];

  float lacc = 0.f;
  for (int r = 0; r < 4; r++) {
    const int row = blockIdx.x * 16 + r * 4 + wv;
    float p = 0.f;
    if (lane < 40) {
      const float v = ws_h2[(size_t)row * 40 + lane];
      const float bn = v * b2j + c2j;
      const float xn = sigm(betaj * bn);
      p = (alphaj * (1.f - xn) * v + xn * v) * wj;
    }
    const float logit = wsum64(p) + b3;
    if (lane == 0) {
      out[row] = 1.f / (1.f + expf(-logit));
      const float lab = (float)lb[row];
      lacc += fmaxf(logit, 0.f) - logit * lab + log1pf(expf(-fabsf(logit)));
    }
  }
  if (lane == 0) wls[wv] = lacc;
  __syncthreads();
  if (tid == 0) atomicAdd(g_loss, (double)(wls[0] + wls[1] + wls[2] + wls[3]));
}

__global__ void k8(const double* __restrict__ g_loss, float* __restrict__ out) {
  out[NB] = (float)(g_loss[0] * (1.0 / (double)NB));
}

} // namespace

extern "C" void kernel_launch(void* const* d_in, const int* in_sizes, int n_in,
                              void* d_out, int out_size, void* d_ws, size_t ws_size,
                              hipStream_t stream) {
  const int* iid       = (const int*)d_in[0];
  const int* aid       = (const int*)d_in[1];
  const int* lb        = (const int*)d_in[2];
  const int* hist_iid  = (const int*)d_in[3];
  const int* hist_aid  = (const int*)d_in[4];
  const int* hist_rate = (const int*)d_in[5];
  const float* item_tab = (const float*)d_in[6];
  const float* cate_tab = (const float*)d_in[7];
  const float* rate_tab = (const float*)d_in[8];
  const float* au_W1    = (const float*)d_in[9];
  const float* au_b1    = (const float*)d_in[10];
  const float* au_alpha = (const float*)d_in[11];
  const float* au_beta  = (const float*)d_in[12];
  const float* au_gamma = (const float*)d_in[13];
  const float* au_bbeta = (const float*)d_in[14];
  const float* au_W2    = (const float*)d_in[15];
  const float* au_b2    = (const float*)d_in[16];
  const float* l1_W     = (const float*)d_in[17];
  const float* l1_b     = (const float*)d_in[18];
  const float* d1_alpha = (const float*)d_in[19];
  const float* d1_beta  = (const float*)d_in[20];
  const float* d1_gamma = (const float*)d_in[21];
  const float* d1_bbeta = (const float*)d_in[22];
  const float* l2_W     = (const float*)d_in[23];
  const float* l2_b     = (const float*)d_in[24];
  const float* d2_alpha = (const float*)d_in[25];
  const float* d2_beta  = (const float*)d_in[26];
  const float* d2_gamma = (const float*)d_in[27];
  const float* d2_bbeta = (const float*)d_in[28];
  const float* l3_W     = (const float*)d_in[29];
  const float* l3_b     = (const float*)d_in[30];
  float* out = (float*)d_out;

  double* g = (double*)d_ws;
  double* g_au_sum = g;
  double* g_au_sq  = g + 36;
  double* g_d1_sum = g + 72;
  double* g_d1_sq  = g + 152;
  double* g_d2_sum = g + 232;
  double* g_d2_sq  = g + 272;
  double* g_loss   = g + 312;
  float* fbase  = (float*)((char*)d_ws + 4096);
  float* ws_y   = fbase;                       // NB*180
  float* ws_w   = fbase + (size_t)NB * 180;    // NB*5
  float* ws_h1  = fbase + (size_t)NB * 185;    // NB*80
  float* ws_h2  = fbase + (size_t)NB * 265;    // NB*40
  int*   ws_hi  = (int*)(fbase + (size_t)NB * 305);  // NB*5
  int*   ws_ha  = ws_hi + (size_t)NB * NK;
  int*   ws_hr  = ws_ha + (size_t)NB * NK;

  hipMemsetAsync(d_ws, 0, 313 * sizeof(double), stream);
  dim3 grd(NB / 16);
  k1<<<grd, 512, 0, stream>>>(iid, aid, hist_iid, hist_aid, hist_rate,
                              item_tab, cate_tab, au_W1, au_b1,
                              ws_y, ws_w, ws_hi, ws_ha, ws_hr, g_au_sum, g_au_sq);
  k3<<<grd, 512, 0, stream>>>(iid, aid, item_tab, cate_tab, rate_tab,
                              au_alpha, au_beta, au_gamma, au_bbeta, au_W2, au_b2,
                              l1_W, l1_b, ws_y, ws_w, ws_hi, ws_ha, ws_hr,
                              g_au_sum, g_au_sq, ws_h1, g_d1_sum, g_d1_sq);
  k5<<<grd, 256, 0, stream>>>(d1_alpha, d1_beta, d1_gamma, d1_bbeta, l2_W, l2_b,
                              ws_h1, g_d1_sum, g_d1_sq, ws_h2, g_d2_sum, g_d2_sq);
  k7<<<grd, 256, 0, stream>>>(lb, d2_alpha, d2_beta, d2_gamma, d2_bbeta, l3_W, l3_b,
                              ws_h2, g_d2_sum, g_d2_sq, out, g_loss);
  k8<<<1, 1, 0, stream>>>(g_loss, out);
}

// Round 6
// 185.068 us; speedup vs baseline: 1.1342x; 1.0587x over previous
//
#include <hip/hip_runtime.h>
#include <cmath>

namespace {
constexpr int NB = 16384;
constexpr int NS = 50;
constexpr int NK = 5;
constexpr int NH = 32;

typedef __attribute__((ext_vector_type(8))) short bf16x8;
typedef __attribute__((ext_vector_type(4))) float f32x4;

__device__ __forceinline__ float wsum64(float v) {
#pragma unroll
  for (int off = 32; off; off >>= 1) v += __shfl_xor(v, off, 64);
  return v;
}

__device__ __forceinline__ float sigm(float x) { return 1.0f / (1.0f + expf(-x)); }

__device__ __forceinline__ unsigned short f2bf(float f) {
  union { float f; unsigned u; } v; v.f = f;
  unsigned r = v.u + 0x7fffu + ((v.u >> 16) & 1u);
  return (unsigned short)(r >> 16);
}

// ---- Kernel 1: embeddings, sim, top-5, x @ au_W1 via MFMA, au-BN stats ------
// 512 thr = 8 waves; 16 rows/block, 2 rows per wave.  (R4-verbatim sim/top-k:
// selection-critical arithmetic — do not reorder the dot-product sums.)
__global__ __launch_bounds__(512) void k1(
    const int* __restrict__ iid, const int* __restrict__ aid,
    const int* __restrict__ hist_iid, const int* __restrict__ hist_aid,
    const int* __restrict__ hist_rate,
    const float* __restrict__ item_tab, const float* __restrict__ cate_tab,
    const float* __restrict__ au_W1, const float* __restrict__ au_b1,
    float* __restrict__ ws_y, float* __restrict__ ws_w,
    int* __restrict__ ws_hi, int* __restrict__ ws_ha, int* __restrict__ ws_hr,
    double* __restrict__ g_au_sum, double* __restrict__ g_au_sq)
{
  const int tid = threadIdx.x;
  const int lane = tid & 63;
  const int wv = tid >> 6;

  __shared__ alignas(16) unsigned short w1t[48][136]; // B: [n][k], bf16, k<128
  __shared__ alignas(16) unsigned short xb[80][136];  // A: [m][k], bf16
  __shared__ float icsh[8][64];
  __shared__ float crossm[80];
  __shared__ float w1c[36], b1s[36];
  __shared__ float psum[36], psq[36];

  // stage W1 (skip row 64 = cross row; K remapped to 128)
  for (int e = tid; e < 48 * 136; e += 512) {
    const int n = e / 136, k = e - 136 * n;
    float v = 0.f;
    if (n < 36 && k < 128) {
      const int i = (k < 64) ? k : (k + 1);
      v = au_W1[i * 36 + n];
    }
    w1t[n][k] = f2bf(v);
  }
  if (tid < 36) {
    w1c[tid] = au_W1[64 * 36 + tid];
    b1s[tid] = au_b1[tid];
    psum[tid] = 0.f; psq[tid] = 0.f;
  }

  for (int r = 0; r < 2; r++) {
    const int lm = r * 8 + wv;
    const int row = blockIdx.x * 16 + lm;

    const int iv = iid[row];
    const int cv = aid[row];
    const float ic = (lane < 32) ? item_tab[iv * NH + lane] : cate_tab[cv * NH + lane - 32];
    icsh[wv][lane] = ic;
    const float n1 = sqrtf(wsum64(ic * ic));

    int hi = 0, ha = 0, rv = 0;
    float dotv = 0.f, sim = -INFINITY;
    if (lane < NS) {
      hi = hist_iid[row * NS + lane];
      ha = hist_aid[row * NS + lane];
      rv = hist_rate[row * NS + lane];
      const float4* ip = reinterpret_cast<const float4*>(item_tab + (size_t)hi * NH);
      const float4* cp = reinterpret_cast<const float4*>(cate_tab + (size_t)ha * NH);
      const float* ics = icsh[wv];
      float n2sq = 0.f;
#pragma unroll
      for (int q = 0; q < 8; q++) {
        float4 a = ip[q];
        dotv += ics[4*q+0]*a.x + ics[4*q+1]*a.y + ics[4*q+2]*a.z + ics[4*q+3]*a.w;
        n2sq += a.x*a.x + a.y*a.y + a.z*a.z + a.w*a.w;
      }
#pragma unroll
      for (int q = 0; q < 8; q++) {
        float4 a = cp[q];
        dotv += ics[32+4*q+0]*a.x + ics[32+4*q+1]*a.y + ics[32+4*q+2]*a.z + ics[32+4*q+3]*a.w;
        n2sq += a.x*a.x + a.y*a.y + a.z*a.z + a.w*a.w;
      }
      sim = dotv / fmaxf(n1 * sqrtf(n2sq), 1e-8f);
    }

    // top-5: descending value, ascending-index tie-break
    float simw = sim;
    const int si = (lane < NS) ? lane : 1000;
    float vals[NK]; int idxs[NK];
#pragma unroll
    for (int rr = 0; rr < NK; rr++) {
      float v = simw; int ii = si;
#pragma unroll
      for (int off = 32; off; off >>= 1) {
        float ov = __shfl_xor(v, off, 64);
        int   oi = __shfl_xor(ii, off, 64);
        if (ov > v || (ov == v && oi < ii)) { v = ov; ii = oi; }
      }
      vals[rr] = v; idxs[rr] = ii;
      if (si == ii) simw = -INFINITY;
    }

    const float ssumw = vals[0] + vals[1] + vals[2] + vals[3] + vals[4] + 1e-8f;
#pragma unroll
    for (int k = 0; k < NK; k++) {
      const float wk = vals[k] / ssumw;
      const float crossk = wk * __shfl(dotv, idxs[k], 64);
      const int hik = __shfl(hi, idxs[k], 64);
      const int hak = __shfl(ha, idxs[k], 64);
      const int rvk = __shfl(rv, idxs[k], 64);
      const float e = (lane < 32) ? item_tab[hik * NH + lane] : cate_tab[hak * NH + lane - 32];
      const int m = lm * 5 + k;
      xb[m][lane] = f2bf(wk * e);
      xb[m][64 + lane] = f2bf(ic);
      if (lane == 0) crossm[m] = crossk;
      if (lane == k) {
        ws_w[row * NK + k] = wk;
        ws_hi[row * NK + k] = hik;
        ws_ha[row * NK + k] = hak;
        ws_hr[row * NK + k] = rvk;
      }
    }
  }
  __syncthreads();

  // MFMA GEMM: M=80 (5 tiles), N=36->48 (3 tiles), K=128 (4 steps)
  const int l15 = lane & 15, lhi = lane >> 4;
  for (int t = wv; t < 15; t += 8) {
    const int mt = t / 3, nt = t - 3 * mt;
    f32x4 acc = {0.f, 0.f, 0.f, 0.f};
#pragma unroll
    for (int ks = 0; ks < 4; ks++) {
      const int k0 = ks * 32 + lhi * 8;
      const bf16x8 a = *reinterpret_cast<const bf16x8*>(&xb[mt * 16 + l15][k0]);
      const bf16x8 b = *reinterpret_cast<const bf16x8*>(&w1t[nt * 16 + l15][k0]);
      acc = __builtin_amdgcn_mfma_f32_16x16x32_bf16(a, b, acc, 0, 0, 0);
    }
    const int n = nt * 16 + l15;
    if (n < 36) {
      const float w1cn = w1c[n], b1n = b1s[n];
      float ls = 0.f, lq = 0.f;
#pragma unroll
      for (int reg = 0; reg < 4; reg++) {
        const int m = mt * 16 + 4 * lhi + reg;
        const float y = acc[reg] + b1n + crossm[m] * w1cn;
        ws_y[(size_t)(blockIdx.x * 80 + m) * 36 + n] = y;
        ls += y; lq += y * y;
      }
      atomicAdd(&psum[n], ls);
      atomicAdd(&psq[n], lq);
    }
  }
  __syncthreads();
  if (tid < 36) {
    atomicAdd(&g_au_sum[tid], (double)psum[tid]);
    atomicAdd(&g_au_sq[tid], (double)psq[tid]);
  }
}

// ---- Kernel 3: dice3, au_out, final_hist, res @ l1_W via MFMA, d1 stats -----
// 512 thr = 8 waves; 64 rows/block (grid 256), 8 rows per wave. M=64, N=80, K=160.
__global__ __launch_bounds__(512) void k3(
    const int* __restrict__ iid, const int* __restrict__ aid,
    const float* __restrict__ item_tab, const float* __restrict__ cate_tab,
    const float* __restrict__ rate_tab,
    const float* __restrict__ au_alpha, const float* __restrict__ au_beta,
    const float* __restrict__ au_gamma, const float* __restrict__ au_bbeta,
    const float* __restrict__ au_W2, const float* __restrict__ au_b2,
    const float* __restrict__ l1_W, const float* __restrict__ l1_b,
    const float* __restrict__ ws_y, const float* __restrict__ ws_w,
    const int* __restrict__ ws_hi, const int* __restrict__ ws_ha,
    const int* __restrict__ ws_hr,
    const double* __restrict__ g_au_sum, const double* __restrict__ g_au_sq,
    float* __restrict__ ws_h1, double* __restrict__ g_d1_sum, double* __restrict__ g_d1_sq)
{
  const int tid = threadIdx.x, lane = tid & 63, wv = tid >> 6;
  __shared__ alignas(16) unsigned short l1t[80][168]; // B: [n][k], k<160
  __shared__ alignas(16) unsigned short resb[64][168];
  __shared__ float asc[36], bsc[36];
  __shared__ float psum[80], psq[80];

  for (int e = tid; e < 80 * 168; e += 512) {
    const int n = e / 168, k = e - 168 * n;
    l1t[n][k] = (k < 160) ? f2bf(l1_W[k * 80 + n]) : (unsigned short)0;
  }
  if (tid < 36) {
    const double m = g_au_sum[tid] * (1.0 / ((double)NB * NK));
    const double var = g_au_sq[tid] * (1.0 / ((double)NB * NK)) - m * m;
    const float rstd = (float)(1.0 / sqrt(var + 1e-8));
    const float g = au_gamma[tid] * rstd;
    asc[tid] = g; bsc[tid] = au_bbeta[tid] - (float)m * g;
  }
  if (tid < 80) { psum[tid] = 0.f; psq[tid] = 0.f; }
  __syncthreads();

  float aj = 0, bj = 0, betaj = 0, alphaj = 0, w2j = 0;
  if (lane < 36) {
    aj = asc[lane]; bj = bsc[lane];
    betaj = au_beta[lane]; alphaj = au_alpha[lane]; w2j = au_W2[lane];
  }
  const float bias2 = au_b2[0];

  for (int r = 0; r < 8; r++) {
    const int lm = r * 8 + wv;
    const int row = blockIdx.x * 64 + lm;

    float aout[NK];
#pragma unroll
    for (int k = 0; k < NK; k++) {
      float p = 0.f;
      if (lane < 36) {
        const float yv = ws_y[(size_t)row * 180 + k * 36 + lane];
        const float bn = yv * aj + bj;
        const float xn = sigm(betaj * bn);
        p = (alphaj * (1.f - xn) * yv + xn * yv) * w2j;
      }
      aout[k] = wsum64(p) + bias2;
    }

    const int iv = iid[row], cv = aid[row];
    const float ic = (lane < 32) ? item_tab[iv * NH + lane] : cate_tab[cv * NH + lane - 32];
    float fh0 = 0.f, fh1 = 0.f;
#pragma unroll
    for (int k = 0; k < NK; k++) {
      const int hik = ws_hi[row * NK + k];
      const int hak = ws_ha[row * NK + k];
      const int rvk = ws_hr[row * NK + k];
      const float wk = ws_w[row * NK + k];
      const float e = (lane < 32) ? item_tab[hik * NH + lane] : cate_tab[hak * NH + lane - 32];
      fh0 = fmaf(wk * e, aout[k], fh0);
      if (lane < 32) fh1 = fmaf(rate_tab[rvk * NH + lane], aout[k], fh1);
    }
    resb[lm][lane] = f2bf(ic);
    resb[lm][64 + lane] = f2bf(fh0);
    if (lane < 32) resb[lm][128 + lane] = f2bf(fh1);
  }
  __syncthreads();

  // GEMM: M=64 (4 tiles) x N=80 (5 tiles), K=160 (5 steps); 20 tiles over 8 waves
  const int l15 = lane & 15, lhi = lane >> 4;
  for (int t = wv; t < 20; t += 8) {
    const int mt = t / 5, nt = t - 5 * mt;
    f32x4 acc = {0.f, 0.f, 0.f, 0.f};
#pragma unroll
    for (int ks = 0; ks < 5; ks++) {
      const int k0 = ks * 32 + lhi * 8;
      const bf16x8 a = *reinterpret_cast<const bf16x8*>(&resb[mt * 16 + l15][k0]);
      const bf16x8 b = *reinterpret_cast<const bf16x8*>(&l1t[nt * 16 + l15][k0]);
      acc = __builtin_amdgcn_mfma_f32_16x16x32_bf16(a, b, acc, 0, 0, 0);
    }
    const int n = nt * 16 + l15;
    const float bn = l1_b[n];
    float ls = 0.f, lq = 0.f;
#pragma unroll
    for (int reg = 0; reg < 4; reg++) {
      const int m = mt * 16 + 4 * lhi + reg;
      const float h = acc[reg] + bn;
      ws_h1[(size_t)(blockIdx.x * 64 + m) * 80 + n] = h;
      ls += h; lq += h * h;
    }
    atomicAdd(&psum[n], ls);
    atomicAdd(&psq[n], lq);
  }
  __syncthreads();
  if (tid < 80) {
    atomicAdd(&g_d1_sum[tid], (double)psum[tid]);
    atomicAdd(&g_d1_sq[tid], (double)psq[tid]);
  }
}

// ---- Kernel 5: dice2(h1), h @ l2_W via MFMA, d2 stats -----------------------
// 512 thr = 8 waves; 32 rows/block (grid 512). M=32, N=40->48, K=80->96.
__global__ __launch_bounds__(512) void k5(
    const float* __restrict__ d1_alpha, const float* __restrict__ d1_beta,
    const float* __restrict__ d1_gamma, const float* __restrict__ d1_bbeta,
    const float* __restrict__ l2_W, const float* __restrict__ l2_b,
    const float* __restrict__ ws_h1,
    const double* __restrict__ g_d1_sum, const double* __restrict__ g_d1_sq,
    float* __restrict__ ws_h2, double* __restrict__ g_d2_sum, double* __restrict__ g_d2_sq)
{
  const int tid = threadIdx.x, lane = tid & 63, wv = tid >> 6;
  __shared__ alignas(16) unsigned short l2t[48][104];
  __shared__ alignas(16) unsigned short h1b[32][104];
  __shared__ float a1[80], c1[80];
  __shared__ float psum[40], psq[40];

  for (int e = tid; e < 48 * 104; e += 512) {
    const int n = e / 104, k = e - 104 * n;
    l2t[n][k] = (n < 40 && k < 80) ? f2bf(l2_W[k * 40 + n]) : (unsigned short)0;
  }
  if (tid < 80) {
    const double m = g_d1_sum[tid] * (1.0 / (double)NB);
    const double var = g_d1_sq[tid] * (1.0 / (double)NB) - m * m;
    const float rstd = (float)(1.0 / sqrt(var + 1e-8));
    const float g = d1_gamma[tid] * rstd;
    a1[tid] = g; c1[tid] = d1_bbeta[tid] - (float)m * g;
  }
  if (tid < 40) { psum[tid] = 0.f; psq[tid] = 0.f; }
  __syncthreads();

  for (int r = 0; r < 4; r++) {
    const int lm = r * 8 + wv;
    const int row = blockIdx.x * 32 + lm;
    {
      const float v = ws_h1[(size_t)row * 80 + lane];
      const float bn = v * a1[lane] + c1[lane];
      const float xn = sigm(d1_beta[lane] * bn);
      h1b[lm][lane] = f2bf(d1_alpha[lane] * (1.f - xn) * v + xn * v);
    }
    const int o = 64 + lane;
    if (lane < 16) {
      const float v = ws_h1[(size_t)row * 80 + o];
      const float bn = v * a1[o] + c1[o];
      const float xn = sigm(d1_beta[o] * bn);
      h1b[lm][o] = f2bf(d1_alpha[o] * (1.f - xn) * v + xn * v);
    } else if (lane < 32) {
      h1b[lm][o] = 0;  // zero pad k=80..95
    }
  }
  __syncthreads();

  // GEMM: M=32 (2 tiles) x N=48 (3 tiles), K=96 (3 steps); 6 tiles over 8 waves
  const int l15 = lane & 15, lhi = lane >> 4;
  for (int t = wv; t < 6; t += 8) {
    const int mt = t / 3, nt = t - 3 * mt;
    f32x4 acc = {0.f, 0.f, 0.f, 0.f};
#pragma unroll
    for (int ks = 0; ks < 3; ks++) {
      const int k0 = ks * 32 + lhi * 8;
      const bf16x8 a = *reinterpret_cast<const bf16x8*>(&h1b[mt * 16 + l15][k0]);
      const bf16x8 b = *reinterpret_cast<const bf16x8*>(&l2t[nt * 16 + l15][k0]);
      acc = __builtin_amdgcn_mfma_f32_16x16x32_bf16(a, b, acc, 0, 0, 0);
    }
    const int n = nt * 16 + l15;
    if (n < 40) {
      const float bn = l2_b[n];
      float ls = 0.f, lq = 0.f;
#pragma unroll
      for (int reg = 0; reg < 4; reg++) {
        const int m = mt * 16 + 4 * lhi + reg;
        const float h = acc[reg] + bn;
        ws_h2[(size_t)(blockIdx.x * 32 + m) * 40 + n] = h;
        ls += h; lq += h * h;
      }
      atomicAdd(&psum[n], ls);
      atomicAdd(&psq[n], lq);
    }
  }
  __syncthreads();
  if (tid < 40) {
    atomicAdd(&g_d2_sum[tid], (double)psum[tid]);
    atomicAdd(&g_d2_sq[tid], (double)psq[tid]);
  }
}

// ---- Kernel 7: dice2(h2), logits, probs, loss -------------------------------
__global__ __launch_bounds__(256) void k7(
    const int* __restrict__ lb,
    const float* __restrict__ d2_alpha, const float* __restrict__ d2_beta,
    const float* __restrict__ d2_gamma, const float* __restrict__ d2_bbeta,
    const float* __restrict__ l3_W, const float* __restrict__ l3_b,
    const float* __restrict__ ws_h2,
    const double* __restrict__ g_d2_sum, const double* __restrict__ g_d2_sq,
    float* __restrict__ out, double* __restrict__ g_loss)
{
  const int tid = threadIdx.x, lane = tid & 63, wv = tid >> 6;
  __shared__ float a2[40], c2[40];
  __shared__ float wls[4];
  if (tid < 40) {
    const double m = g_d2_sum[tid] * (1.0 / (double)NB);
    const double var = g_d2_sq[tid] * (1.0 / (double)NB) - m * m;
    const float rstd = (float)(1.0 / sqrt(var + 1e-8));
    const float g = d2_gamma[tid] * rstd;
    a2[tid] = g; c2[tid] = d2_bbeta[tid] - (float)m * g;
  }
  __syncthreads();

  float wj = 0, b2j = 0, c2j = 0, betaj = 0, alphaj = 0;
  if (lane < 40) {
    wj = l3_W[lane]; b2j = a2[lane]; c2j = c2[lane];
    betaj = d2_beta[lane]; alphaj = d2_alpha[lane];
  }
  const float b3 = l3_b[0];

  float lacc = 0.f;
  for (int r = 0; r < 4; r++) {
    const int row = blockIdx.x * 16 + r * 4 + wv;
    float p = 0.f;
    if (lane < 40) {
      const float v = ws_h2[(size_t)row * 40 + lane];
      const float bn = v * b2j + c2j;
      const float xn = sigm(betaj * bn);
      p = (alphaj * (1.f - xn) * v + xn * v) * wj;
    }
    const float logit = wsum64(p) + b3;
    if (lane == 0) {
      out[row] = 1.f / (1.f + expf(-logit));
      const float lab = (float)lb[row];
      lacc += fmaxf(logit, 0.f) - logit * lab + log1pf(expf(-fabsf(logit)));
    }
  }
  if (lane == 0) wls[wv] = lacc;
  __syncthreads();
  if (tid == 0) atomicAdd(g_loss, (double)(wls[0] + wls[1] + wls[2] + wls[3]));
}

__global__ void k8(const double* __restrict__ g_loss, float* __restrict__ out) {
  out[NB] = (float)(g_loss[0] * (1.0 / (double)NB));
}

} // namespace

extern "C" void kernel_launch(void* const* d_in, const int* in_sizes, int n_in,
                              void* d_out, int out_size, void* d_ws, size_t ws_size,
                              hipStream_t stream) {
  const int* iid       = (const int*)d_in[0];
  const int* aid       = (const int*)d_in[1];
  const int* lb        = (const int*)d_in[2];
  const int* hist_iid  = (const int*)d_in[3];
  const int* hist_aid  = (const int*)d_in[4];
  const int* hist_rate = (const int*)d_in[5];
  const float* item_tab = (const float*)d_in[6];
  const float* cate_tab = (const float*)d_in[7];
  const float* rate_tab = (const float*)d_in[8];
  const float* au_W1    = (const float*)d_in[9];
  const float* au_b1    = (const float*)d_in[10];
  const float* au_alpha = (const float*)d_in[11];
  const float* au_beta  = (const float*)d_in[12];
  const float* au_gamma = (const float*)d_in[13];
  const float* au_bbeta = (const float*)d_in[14];
  const float* au_W2    = (const float*)d_in[15];
  const float* au_b2    = (const float*)d_in[16];
  const float* l1_W     = (const float*)d_in[17];
  const float* l1_b     = (const float*)d_in[18];
  const float* d1_alpha = (const float*)d_in[19];
  const float* d1_beta  = (const float*)d_in[20];
  const float* d1_gamma = (const float*)d_in[21];
  const float* d1_bbeta = (const float*)d_in[22];
  const float* l2_W     = (const float*)d_in[23];
  const float* l2_b     = (const float*)d_in[24];
  const float* d2_alpha = (const float*)d_in[25];
  const float* d2_beta  = (const float*)d_in[26];
  const float* d2_gamma = (const float*)d_in[27];
  const float* d2_bbeta = (const float*)d_in[28];
  const float* l3_W     = (const float*)d_in[29];
  const float* l3_b     = (const float*)d_in[30];
  float* out = (float*)d_out;

  double* g = (double*)d_ws;
  double* g_au_sum = g;
  double* g_au_sq  = g + 36;
  double* g_d1_sum = g + 72;
  double* g_d1_sq  = g + 152;
  double* g_d2_sum = g + 232;
  double* g_d2_sq  = g + 272;
  double* g_loss   = g + 312;
  float* fbase  = (float*)((char*)d_ws + 4096);
  float* ws_y   = fbase;                       // NB*180
  float* ws_w   = fbase + (size_t)NB * 180;    // NB*5
  float* ws_h1  = fbase + (size_t)NB * 185;    // NB*80
  float* ws_h2  = fbase + (size_t)NB * 265;    // NB*40
  int*   ws_hi  = (int*)(fbase + (size_t)NB * 305);  // NB*5
  int*   ws_ha  = ws_hi + (size_t)NB * NK;
  int*   ws_hr  = ws_ha + (size_t)NB * NK;

  hipMemsetAsync(d_ws, 0, 313 * sizeof(double), stream);
  k1<<<dim3(NB / 16), 512, 0, stream>>>(iid, aid, hist_iid, hist_aid, hist_rate,
                              item_tab, cate_tab, au_W1, au_b1,
                              ws_y, ws_w, ws_hi, ws_ha, ws_hr, g_au_sum, g_au_sq);
  k3<<<dim3(NB / 64), 512, 0, stream>>>(iid, aid, item_tab, cate_tab, rate_tab,
                              au_alpha, au_beta, au_gamma, au_bbeta, au_W2, au_b2,
                              l1_W, l1_b, ws_y, ws_w, ws_hi, ws_ha, ws_hr,
                              g_au_sum, g_au_sq, ws_h1, g_d1_sum, g_d1_sq);
  k5<<<dim3(NB / 32), 512, 0, stream>>>(d1_alpha, d1_beta, d1_gamma, d1_bbeta, l2_W, l2_b,
                              ws_h1, g_d1_sum, g_d1_sq, ws_h2, g_d2_sum, g_d2_sq);
  k7<<<dim3(NB / 16), 256, 0, stream>>>(lb, d2_alpha, d2_beta, d2_gamma, d2_bbeta, l3_W, l3_b,
                              ws_h2, g_d2_sum, g_d2_sq, out, g_loss);
  k8<<<1, 1, 0, stream>>>(g_loss, out);
}